// Round 14
// baseline (284.061 us; speedup 1.0000x reference)
//
#include <hip/hip_runtime.h>

#define N_NODES 50000
#define N_EDGES 1600000
#define ET (N_EDGES + N_NODES)   // edges + self-loops
#define DF 128                   // feature / hidden dim
#define SLOPE 0.2f

#define NB 196        // coarse buckets: dst >> 8 (50000/256)
#define BCAP 10240    // slots per bucket (avg 8448, sigma ~92 -> +19 sigma)
#define P1_CHUNK 4096 // edges per bin block (16 per thread)
#define GEMM_BLOCKS ((N_NODES + 127) / 128)          // 391 (128-row tile)
#define BIN_BLOCKS ((ET + P1_CHUNK - 1) / P1_CHUNK)  // 403

typedef __attribute__((ext_vector_type(4))) float floatx4;     // MFMA C/D
typedef __attribute__((ext_vector_type(8))) _Float16 half8;    // 8 fp16 (16 B)
typedef __attribute__((ext_vector_type(2))) _Float16 half2v;   // fdot2 operand

// ---------------------------------------------------------------------------
// One-time W prep (also zeroes g_count). Splits the four 128x128 W matrices
// into fp16 hi + fp16 residual lo, stored TRANSPOSED [c][k].
// ---------------------------------------------------------------------------
__global__ __launch_bounds__(256) void wconv4(
    const float* __restrict__ W0, const float* __restrict__ W1,
    const float* __restrict__ W2, const float* __restrict__ W3,
    _Float16* __restrict__ Wh, _Float16* __restrict__ Wl,
    int* __restrict__ g_count)
{
    if (blockIdx.x == 0) g_count[threadIdx.x] = 0;
    int idx = blockIdx.x * 256 + threadIdx.x;   // 0..65535
    int m = idx >> 14, rem = idx & 16383;
    const float* W = (m == 0) ? W0 : (m == 1) ? W1 : (m == 2) ? W2 : W3;
    int c = rem >> 7, k = rem & 127;
    float v = W[k * 128 + c];
    _Float16 h = (_Float16)v;
    Wh[(size_t)m * 16384 + c * 128 + k] = h;
    Wl[(size_t)m * 16384 + c * 128 + k] = (_Float16)(v - (float)h);
}

__device__ __forceinline__ half8 load_h8(const float* p) {
    float4 a = *(const float4*)(p);
    float4 b = *(const float4*)(p + 4);
    half8 h;
    h[0] = (_Float16)a.x; h[1] = (_Float16)a.y;
    h[2] = (_Float16)a.z; h[3] = (_Float16)a.w;
    h[4] = (_Float16)b.x; h[5] = (_Float16)b.y;
    h[6] = (_Float16)b.z; h[7] = (_Float16)b.w;
    return h;
}
__device__ __forceinline__ half8 load_h8(const _Float16* p) {
    return *(const half8*)p;
}

// ---------------------------------------------------------------------------
// GEMM body: fp16 MFMA, L+R merged, 128-row tile, BK=32, 64 MFMA/K-iter/wave.
// Each wave covers 32 rows (2 m-subtiles); every W B-fragment LDS read feeds
// 2 MFMAs, and W restaging per output row is halved vs the 64-row tile.
// acc = X16*Wh + X16*Wl. Outputs fp16 standard [M][128]. LDS 51.2 KB.
// ---------------------------------------------------------------------------
template<typename T>
__device__ __forceinline__ void gemm_body(
    int bid, const T* __restrict__ X,
    const _Float16* __restrict__ WhL, const _Float16* __restrict__ WlL,
    const _Float16* __restrict__ WhR, const _Float16* __restrict__ WlR,
    _Float16* __restrict__ outL, _Float16* __restrict__ outR, int M, char* smem_)
{
    _Float16* xs  = (_Float16*)smem_;      // 128*40 (10,240 B)
    _Float16* whL = xs + 128 * 40;         // 128*40 each
    _Float16* wlL = whL + 128 * 40;
    _Float16* whR = wlL + 128 * 40;
    _Float16* wlR = whR + 128 * 40;        // total 51,200 B

    const int t = threadIdx.x;
    const int row0 = bid * 128;
    const int lane = t & 63, wv = t >> 6;
    const int lm = lane & 15, quad = lane >> 4;
    const int m0 = wv * 32;                // wave rows m0..m0+31 (2 subtiles)

    floatx4 accL[2][8], accR[2][8];
#pragma unroll
    for (int i = 0; i < 2; i++)
#pragma unroll
        for (int j = 0; j < 8; j++) { accL[i][j] = (floatx4)0.f; accR[i][j] = (floatx4)0.f; }

    const int sr = t >> 1;          // X stage: row 0..127 (2 thr/row)
    const int sc = (t & 1) * 16;    // X stage: k half (16 elems)
    const int wn = t >> 1;          // W stage: col 0..127 (2 thr/col)
    const int wkh = (t & 1) * 16;   // W stage: k half

    for (int kb = 0; kb < 128; kb += 32) {
        int xrow = row0 + sr; if (xrow >= M) xrow = M - 1;
        half8 xv0 = load_h8(X + (size_t)xrow * DF + kb + sc);
        half8 xv1 = load_h8(X + (size_t)xrow * DF + kb + sc + 8);
        *(half8*)&xs[sr * 40 + sc]     = xv0;
        *(half8*)&xs[sr * 40 + sc + 8] = xv1;

        const size_t wofs = (size_t)wn * 128 + kb + wkh;
        {
            const uint4* p = (const uint4*)(WhL + wofs);
            uint4 a = p[0], b = p[1];
            *(uint4*)&whL[wn * 40 + wkh] = a; *(uint4*)&whL[wn * 40 + wkh + 8] = b;
        }
        {
            const uint4* p = (const uint4*)(WlL + wofs);
            uint4 a = p[0], b = p[1];
            *(uint4*)&wlL[wn * 40 + wkh] = a; *(uint4*)&wlL[wn * 40 + wkh + 8] = b;
        }
        {
            const uint4* p = (const uint4*)(WhR + wofs);
            uint4 a = p[0], b = p[1];
            *(uint4*)&whR[wn * 40 + wkh] = a; *(uint4*)&whR[wn * 40 + wkh + 8] = b;
        }
        {
            const uint4* p = (const uint4*)(WlR + wofs);
            uint4 a = p[0], b = p[1];
            *(uint4*)&wlR[wn * 40 + wkh] = a; *(uint4*)&wlR[wn * 40 + wkh + 8] = b;
        }
        __syncthreads();

        half8 af0 = *(const half8*)&xs[(m0 + lm) * 40 + quad * 8];
        half8 af1 = *(const half8*)&xs[(m0 + 16 + lm) * 40 + quad * 8];
#pragma unroll
        for (int nt = 0; nt < 8; nt++) {
            const int bofs = (nt * 16 + lm) * 40 + quad * 8;
            half8 bh = *(const half8*)&whL[bofs];
            half8 bl = *(const half8*)&wlL[bofs];
            accL[0][nt] = __builtin_amdgcn_mfma_f32_16x16x32_f16(af0, bh, accL[0][nt], 0, 0, 0);
            accL[0][nt] = __builtin_amdgcn_mfma_f32_16x16x32_f16(af0, bl, accL[0][nt], 0, 0, 0);
            accL[1][nt] = __builtin_amdgcn_mfma_f32_16x16x32_f16(af1, bh, accL[1][nt], 0, 0, 0);
            accL[1][nt] = __builtin_amdgcn_mfma_f32_16x16x32_f16(af1, bl, accL[1][nt], 0, 0, 0);
            half8 ch = *(const half8*)&whR[bofs];
            half8 cl = *(const half8*)&wlR[bofs];
            accR[0][nt] = __builtin_amdgcn_mfma_f32_16x16x32_f16(af0, ch, accR[0][nt], 0, 0, 0);
            accR[0][nt] = __builtin_amdgcn_mfma_f32_16x16x32_f16(af0, cl, accR[0][nt], 0, 0, 0);
            accR[1][nt] = __builtin_amdgcn_mfma_f32_16x16x32_f16(af1, ch, accR[1][nt], 0, 0, 0);
            accR[1][nt] = __builtin_amdgcn_mfma_f32_16x16x32_f16(af1, cl, accR[1][nt], 0, 0, 0);
        }
        __syncthreads();
    }

#pragma unroll
    for (int mt = 0; mt < 2; mt++) {
#pragma unroll
        for (int nt = 0; nt < 8; nt++) {
            int col = (nt >> 2) * 64 + (nt & 3) * 16 + lm;
#pragma unroll
            for (int r = 0; r < 4; r++) {
                int gr = row0 + m0 + mt * 16 + quad * 4 + r;
                if (gr < M) {
                    size_t o = (size_t)gr * DF + col;
                    outL[o] = (_Float16)accL[mt][nt][r];
                    outR[o] = (_Float16)accR[mt][nt][r];
                }
            }
        }
    }
}

// ---------------------------------------------------------------------------
// Bin body: CSR pass 1 (coarse bucket sort).
// ---------------------------------------------------------------------------
__device__ __forceinline__ void bin_body(
    int bid, const int* __restrict__ ei,
    int* __restrict__ g_count, int* __restrict__ bucket_mem, char* smem_)
{
    int* cnt  = (int*)smem_;
    int* base = cnt + NB;
    int* cnt2 = base + NB;
    const int tid = threadIdx.x;

    for (int i = tid; i < NB; i += 256) { cnt[i] = 0; cnt2[i] = 0; }
    __syncthreads();

    const int e0 = bid * P1_CHUNK;
    int srcv[16], dstv[16];
#pragma unroll
    for (int i = 0; i < 16; i++) {
        int eid = e0 + i * 256 + tid;   // coalesced
        int s = 0, d = -1;
        if (eid < ET) {
            if (eid < N_EDGES) { s = ei[eid]; d = ei[N_EDGES + eid]; }
            else               { s = d = eid - N_EDGES; }
        }
        srcv[i] = s; dstv[i] = d;
        if (d >= 0) atomicAdd(&cnt[d >> 8], 1);
    }
    __syncthreads();
    for (int i = tid; i < NB; i += 256)
        base[i] = (cnt[i] > 0) ? atomicAdd(&g_count[i], cnt[i]) : 0;
    __syncthreads();
#pragma unroll
    for (int i = 0; i < 16; i++) {
        int d = dstv[i];
        if (d >= 0) {
            int b = d >> 8;
            int r = atomicAdd(&cnt2[b], 1);
            int slot = base[b] + r;
            if (slot < BCAP)
                bucket_mem[(size_t)b * BCAP + slot] =
                    (srcv[i] & 0xFFFF) | ((d & 255) << 16);
        }
    }
}

// ---------------------------------------------------------------------------
// Mega-dispatch: blocks [0, GEMM_BLOCKS) = layer-1 GEMM (fp32 input);
// blocks [GEMM_BLOCKS, +BIN_BLOCKS) = CSR bin pass.
// ---------------------------------------------------------------------------
__global__ __launch_bounds__(256) void gemm_bin(
    const float* __restrict__ X,
    const _Float16* __restrict__ Wh, const _Float16* __restrict__ Wl,
    _Float16* __restrict__ outL, _Float16* __restrict__ outR,
    const int* __restrict__ ei,
    int* __restrict__ g_count, int* __restrict__ bucket_mem)
{
    __shared__ char smem[51200];
    if (blockIdx.x < GEMM_BLOCKS)
        gemm_body<float>(blockIdx.x, X, Wh, Wl, Wh + 16384, Wl + 16384,
                         outL, outR, N_NODES, smem);
    else
        bin_body(blockIdx.x - GEMM_BLOCKS, ei, g_count, bucket_mem, smem);
}

// Layer-2 GEMM: fp16 input (layer-1 activations; zero-cvt staging).
__global__ __launch_bounds__(256) void gemm_f16(
    const _Float16* __restrict__ X,
    const _Float16* __restrict__ Wh, const _Float16* __restrict__ Wl,
    _Float16* __restrict__ outL, _Float16* __restrict__ outR)
{
    __shared__ char smem[51200];
    gemm_body<_Float16>(blockIdx.x, X, Wh, Wl, Wh + 16384, Wl + 16384,
                        outL, outR, N_NODES, smem);
}

// ---------------------------------------------------------------------------
// CSR pass 2: one block per bucket, 1024 threads.
// ---------------------------------------------------------------------------
__global__ __launch_bounds__(1024) void csr_pass(const int* __restrict__ g_count,
                                                 const int* __restrict__ bucket_mem,
                                                 int* __restrict__ row_ptr,
                                                 unsigned short* __restrict__ csr_src)
{
    __shared__ int sh_edges[BCAP];
    __shared__ int hist[256], offs[256], excl[256], cnt2[256];
    __shared__ int gsc[256];
    const int b = blockIdx.x, tid = threadIdx.x;

    if (tid < 256) gsc[tid] = (tid < NB) ? g_count[tid] : 0;
    __syncthreads();
    for (int d = 1; d < 256; d <<= 1) {
        int x = 0;
        if (tid < 256 && tid >= d) x = gsc[tid - d];
        __syncthreads();
        if (tid < 256) gsc[tid] += x;
        __syncthreads();
    }
    const int base_csr = (b > 0) ? gsc[b - 1] : 0;

    int m = g_count[b]; if (m > BCAP) m = BCAP;
    if (tid < 256) { hist[tid] = 0; cnt2[tid] = 0; }
    __syncthreads();
    const int* bm = bucket_mem + (size_t)b * BCAP;
    for (int i = tid; i < m; i += 1024) {
        int p = bm[i];
        sh_edges[i] = p;
        atomicAdd(&hist[(p >> 16) & 255], 1);
    }
    __syncthreads();
    if (tid < 256) offs[tid] = hist[tid];
    __syncthreads();
    for (int d = 1; d < 256; d <<= 1) {
        int x = 0;
        if (tid < 256 && tid >= d) x = offs[tid - d];
        __syncthreads();
        if (tid < 256) offs[tid] += x;
        __syncthreads();
    }
    if (tid < 256) {
        excl[tid] = offs[tid] - hist[tid];
        int node = (b << 8) + tid;
        if (node < N_NODES) row_ptr[node] = base_csr + excl[tid];
    }
    if (b == 0 && tid == 0) row_ptr[N_NODES] = ET;
    __syncthreads();
    for (int i = tid; i < m; i += 1024) {
        int p = sh_edges[i];
        int dl = (p >> 16) & 255;
        int r = atomicAdd(&cnt2[dl], 1);
        csr_src[base_csr + excl[dl] + r] = (unsigned short)(p & 0xFFFF);
    }
}

// ---------------------------------------------------------------------------
// Full-width fused scores + softmax + aggregate, 2-deep pipeline (frozen:
// measured service-bound at ~62-63 us across 4 structural variants).
// ---------------------------------------------------------------------------
template<typename TOut>
__global__ __launch_bounds__(256) void fused_agg(
    const _Float16* __restrict__ XL, const _Float16* __restrict__ XR,
    const int* __restrict__ row_ptr, const unsigned short* __restrict__ csr_src,
    const float* __restrict__ att, const float* __restrict__ bias,
    TOut* __restrict__ out)
{
    const int t = threadIdx.x;
    const int wave = t >> 6, l = t & 63;
    const int g = l >> 4, gl = l & 15;       // edge group 0..3, lane in group
    const int n = blockIdx.x * 4 + wave;
    if (n >= N_NODES) return;
    const int beg = row_ptr[n], end = row_ptr[n + 1];

    const int c0 = gl * 8;                   // channels c0..c0+7
    half8 xrh = *(const half8*)(XR + (size_t)n * DF + c0);
    float4 at0 = *(const float4*)(att + c0);
    float4 at1 = *(const float4*)(att + c0 + 4);
    half2v a01 = { (_Float16)at0.x, (_Float16)at0.y };
    half2v a23 = { (_Float16)at0.z, (_Float16)at0.w };
    half2v a45 = { (_Float16)at1.x, (_Float16)at1.y };
    half2v a67 = { (_Float16)at1.z, (_Float16)at1.w };
    const half8 slp = { (_Float16)SLOPE, (_Float16)SLOPE, (_Float16)SLOPE, (_Float16)SLOPE,
                        (_Float16)SLOPE, (_Float16)SLOPE, (_Float16)SLOPE, (_Float16)SLOPE };

    float a0 = 0.f, a1 = 0.f, a2 = 0.f, a3 = 0.f;
    float a4 = 0.f, a5 = 0.f, a6 = 0.f, a7 = 0.f, den = 0.f;

    // pipeline prologue: two octets in flight
    int e0i = beg + g;
    int s0 = (e0i < end) ? csr_src[e0i] : 0;
    half8 hv0 = *(const half8*)(XL + (size_t)s0 * DF + c0);
    int e1i = beg + 4 + g;
    int s1 = (e1i < end) ? csr_src[e1i] : 0;
    half8 hv1 = *(const half8*)(XL + (size_t)s1 * DF + c0);

#define EDGE_STEP(HV, EOK)                                                     \
    {                                                                          \
        half8 msg = HV + xrh;                                                  \
        half8 lk  = __builtin_elementwise_max(msg, msg * slp);                 \
        half2v m01 = { lk[0], lk[1] };                                         \
        half2v m23 = { lk[2], lk[3] };                                         \
        half2v m45 = { lk[4], lk[5] };                                         \
        half2v m67 = { lk[6], lk[7] };                                         \
        float p = __builtin_amdgcn_fdot2(m01, a01, 0.f, false);                \
        p = __builtin_amdgcn_fdot2(m23, a23, p, false);                        \
        p = __builtin_amdgcn_fdot2(m45, a45, p, false);                        \
        p = __builtin_amdgcn_fdot2(m67, a67, p, false);                        \
        p += __shfl_xor(p, 1);                                                 \
        p += __shfl_xor(p, 2);                                                 \
        float e = (EOK) ? __expf(p) : 0.f;                                     \
        a0 += e * (float)HV[0]; a1 += e * (float)HV[1];                        \
        a2 += e * (float)HV[2]; a3 += e * (float)HV[3];                        \
        a4 += e * (float)HV[4]; a5 += e * (float)HV[5];                        \
        a6 += e * (float)HV[6]; a7 += e * (float)HV[7];                        \
        den += e;                                                              \
    }

    for (int j = beg; j < end; j += 8) {
        int en0 = j + 8 + g;
        int sn0 = (en0 < end) ? csr_src[en0] : 0;
        half8 hn0 = *(const half8*)(XL + (size_t)sn0 * DF + c0);
        int en1 = j + 12 + g;
        int sn1 = (en1 < end) ? csr_src[en1] : 0;
        half8 hn1 = *(const half8*)(XL + (size_t)sn1 * DF + c0);

        EDGE_STEP(hv0, (j + g < end))
        EDGE_STEP(hv1, (j + 4 + g < end))

        hv0 = hn0; hv1 = hn1;
    }
#undef EDGE_STEP

#define CMB(x) x += __shfl_xor(x, 16); x += __shfl_xor(x, 32);
    CMB(a0) CMB(a1) CMB(a2) CMB(a3) CMB(a4) CMB(a5) CMB(a6) CMB(a7) CMB(den)
#undef CMB

    if (g == 0) {
        float inv = 1.f / (den + 1e-16f);     // den is this lane's head's total
        float4 b0 = *(const float4*)(bias + c0);
        float4 b1 = *(const float4*)(bias + c0 + 4);
        float o[8];
        o[0] = fmaxf(a0 * inv + b0.x, 0.f);
        o[1] = fmaxf(a1 * inv + b0.y, 0.f);
        o[2] = fmaxf(a2 * inv + b0.z, 0.f);
        o[3] = fmaxf(a3 * inv + b0.w, 0.f);
        o[4] = fmaxf(a4 * inv + b1.x, 0.f);
        o[5] = fmaxf(a5 * inv + b1.y, 0.f);
        o[6] = fmaxf(a6 * inv + b1.z, 0.f);
        o[7] = fmaxf(a7 * inv + b1.w, 0.f);
        TOut* op = out + (size_t)n * DF + c0;
        if constexpr (sizeof(TOut) == 2) {
            half8 hv;
#pragma unroll
            for (int i = 0; i < 8; i++) hv[i] = (_Float16)o[i];
            *(half8*)op = hv;
        } else {
            *(float4*)(op)     = make_float4(o[0], o[1], o[2], o[3]);
            *(float4*)(op + 4) = make_float4(o[4], o[5], o[6], o[7]);
        }
    }
}

// ---------------------------------------------------------------------------
extern "C" void kernel_launch(void* const* d_in, const int* in_sizes, int n_in,
                              void* d_out, int out_size, void* d_ws, size_t ws_size,
                              hipStream_t stream)
{
    (void)in_sizes; (void)n_in; (void)out_size; (void)ws_size;

    const float* x    = (const float*)d_in[0];
    const int*   ei   = (const int*)d_in[1];
    const float* W1l  = (const float*)d_in[2];
    const float* W1r  = (const float*)d_in[3];
    const float* att1 = (const float*)d_in[4];
    const float* b1   = (const float*)d_in[5];
    const float* W2l  = (const float*)d_in[6];
    const float* W2r  = (const float*)d_in[7];
    const float* att2 = (const float*)d_in[8];
    const float* b2   = (const float*)d_in[9];
    float* out = (float*)d_out;

    char* ws = (char*)d_ws;
    size_t off = 0;
    const size_t NF = (size_t)N_NODES * DF * sizeof(float);        // 25.6 MB
    _Float16* A = (_Float16*)(ws + off); off += NF / 2;            // xl fp16 [N][128]
    _Float16* B = (_Float16*)(ws + off); off += NF / 2;            // xr fp16 [N][128]
    _Float16* C = (_Float16*)(ws + off); off += NF / 2;            // layer-1 out fp16
    int* bucket_mem  = (int*)(ws + off); off += (size_t)NB * BCAP * sizeof(int);
    int* g_count     = (int*)(ws + off); off += 256 * sizeof(int);
    int* row_ptr     = (int*)(ws + off); off += (size_t)(N_NODES + 1) * sizeof(int);
    unsigned short* csr_src = (unsigned short*)(ws + off);
    off += ((size_t)ET * sizeof(unsigned short) + 255) & ~(size_t)255;
    _Float16* Wh = (_Float16*)(ws + off); off += 4 * 16384 * sizeof(_Float16);
    _Float16* Wl = (_Float16*)(ws + off); off += 4 * 16384 * sizeof(_Float16);

    // ---- one-time prep: W split (also zeroes g_count) ----
    wconv4<<<256, 256, 0, stream>>>(W1l, W1r, W2l, W2r, Wh, Wl, g_count);

    // ---- layer-1 GEMM + CSR bin pass, overlapped in one dispatch ----
    gemm_bin<<<GEMM_BLOCKS + BIN_BLOCKS, 256, 0, stream>>>(
        x, Wh, Wl, A, B, ei, g_count, bucket_mem);
    csr_pass<<<NB, 1024, 0, stream>>>(g_count, bucket_mem, row_ptr, csr_src);
    fused_agg<_Float16><<<(N_NODES + 3) / 4, 256, 0, stream>>>(
        A, B, row_ptr, csr_src, att1, b1, C);

    // ---- layer 2 ----
    gemm_f16<<<GEMM_BLOCKS, 256, 0, stream>>>(C, Wh + 2 * 16384, Wl + 2 * 16384, A, B);
    fused_agg<float><<<(N_NODES + 3) / 4, 256, 0, stream>>>(
        A, B, row_ptr, csr_src, att2, b2, out);
}